// Round 1
// baseline (1769.596 us; speedup 1.0000x reference)
//
#include <hip/hip_runtime.h>
#include <hip/hip_bf16.h>

#define B_ 4
#define T_ 2048
#define C_ 1024
#define H_ 16
#define D_ 64

using u16x4 = __attribute__((ext_vector_type(4))) unsigned short;
using u16x8 = __attribute__((ext_vector_type(8))) unsigned short;
using s16x8 = __attribute__((ext_vector_type(8))) short;
using f32x4v = __attribute__((ext_vector_type(4))) float;

__device__ inline float bf2f(unsigned short u) {
  return __uint_as_float(((unsigned int)u) << 16);
}
__device__ inline unsigned short f2bf(float f) {
  unsigned int x = __float_as_uint(f);
  unsigned int r = (x + 0x7fffu + ((x >> 16) & 1u)) >> 16;
  return (unsigned short)r;
}

// ---------------- elementwise f32 -> bf16 cast ----------------
__global__ __launch_bounds__(256) void cast_f32_bf16(const float* __restrict__ in,
                                                     ushort* __restrict__ out, int n4) {
  const int stride = gridDim.x * blockDim.x;
  for (int i = blockIdx.x * blockDim.x + threadIdx.x; i < n4; i += stride) {
    float4 v = ((const float4*)in)[i];
    u16x4 o = {f2bf(v.x), f2bf(v.y), f2bf(v.z), f2bf(v.w)};
    ((u16x4*)out)[i] = o;
  }
}

// ---------------- transpose + cast: W[K][N] f32 -> Wt[N][K] bf16 ----------------
__global__ __launch_bounds__(256) void transpose_cast(const float* __restrict__ W,
                                                      ushort* __restrict__ Wt, int K, int N) {
  __shared__ float tile[64][65];
  const int n0 = blockIdx.x * 64, k0 = blockIdx.y * 64;
  const int tid = threadIdx.x;
  const int tr = tid >> 4, tc4 = (tid & 15) * 4;
#pragma unroll
  for (int i = 0; i < 4; ++i) {
    int r = tr + i * 16;
    float4 v = *(const float4*)&W[(size_t)(k0 + r) * N + n0 + tc4];
    tile[r][tc4 + 0] = v.x; tile[r][tc4 + 1] = v.y;
    tile[r][tc4 + 2] = v.z; tile[r][tc4 + 3] = v.w;
  }
  __syncthreads();
#pragma unroll
  for (int i = 0; i < 4; ++i) {
    int n = tr + i * 16;
    u16x4 o;
#pragma unroll
    for (int j = 0; j < 4; ++j) o[j] = f2bf(tile[tc4 + j][n]);
    *(u16x4*)&Wt[(size_t)(n0 + n) * K + k0 + tc4] = o;
  }
}

// ---------------- GEMM: C[M][N] = A[M][K] * Bt[N][K]^T + bias ----------------
// m97 structure: 128x128 tile, BK=64, 4 waves (2x2 of 64x64), global_load_lds(16B).
template <int BF16OUT>
__global__ __launch_bounds__(256) void gemm_bt(const ushort* __restrict__ A,
                                               const ushort* __restrict__ Bt,
                                               const float* __restrict__ bias,
                                               void* __restrict__ Cout,
                                               int M, int N, int K) {
  constexpr int BM = 128, BN = 128, BK = 64;
  __shared__ ushort Alds[BM * BK];
  __shared__ ushort Blds[BN * BK];
  const int tid = threadIdx.x;
  const int lane = tid & 63;
  const int w = tid >> 6;
  const int wr = w >> 1, wc = w & 1;
  const int m0 = blockIdx.y * BM, n0 = blockIdx.x * BN;

  f32x4v acc[4][4] = {};

  const int ra = w * 32 + (lane >> 3);   // row within tile for staging
  const int ca = (lane & 7) * 8;         // k-elem offset for staging

  for (int k0 = 0; k0 < K; k0 += BK) {
#pragma unroll
    for (int i = 0; i < 4; ++i) {
      const ushort* ga = A + (size_t)(m0 + ra + i * 8) * K + k0 + ca;
      __builtin_amdgcn_global_load_lds(
          (const __attribute__((address_space(1))) void*)ga,
          (__attribute__((address_space(3))) void*)&Alds[w * 2048 + i * 512], 16, 0, 0);
      const ushort* gb = Bt + (size_t)(n0 + ra + i * 8) * K + k0 + ca;
      __builtin_amdgcn_global_load_lds(
          (const __attribute__((address_space(1))) void*)gb,
          (__attribute__((address_space(3))) void*)&Blds[w * 2048 + i * 512], 16, 0, 0);
    }
    __syncthreads();
#pragma unroll
    for (int ks = 0; ks < 2; ++ks) {
      s16x8 af[4], bfr[4];
#pragma unroll
      for (int m = 0; m < 4; ++m)
        af[m] = *(const s16x8*)&Alds[(wr * 64 + m * 16 + (lane & 15)) * BK + ks * 32 + ((lane >> 4) * 8)];
#pragma unroll
      for (int n = 0; n < 4; ++n)
        bfr[n] = *(const s16x8*)&Blds[(wc * 64 + n * 16 + (lane & 15)) * BK + ks * 32 + ((lane >> 4) * 8)];
#pragma unroll
      for (int m = 0; m < 4; ++m)
#pragma unroll
        for (int n = 0; n < 4; ++n)
          acc[m][n] = __builtin_amdgcn_mfma_f32_16x16x32_bf16(af[m], bfr[n], acc[m][n], 0, 0, 0);
    }
    __syncthreads();
  }

#pragma unroll
  for (int m = 0; m < 4; ++m) {
    const int rg = m0 + wr * 64 + m * 16 + ((lane >> 4) * 4);
#pragma unroll
    for (int n = 0; n < 4; ++n) {
      const int cg = n0 + wc * 64 + n * 16 + (lane & 15);
      const float bv = bias[cg];
#pragma unroll
      for (int r2 = 0; r2 < 4; ++r2) {
        float v = acc[m][n][r2] + bv;
        if constexpr (BF16OUT)
          ((ushort*)Cout)[(size_t)(rg + r2) * N + cg] = f2bf(v);
        else
          ((float*)Cout)[(size_t)(rg + r2) * N + cg] = v;
      }
    }
  }
}

// ---------------- causal flash attention ----------------
// qkv: [B*T][3C] bf16 (q | k | v). y: [B*T][C] bf16.
// Block: one (b, h, 64-row q tile). 256 threads; 4 threads per q row.
__global__ __launch_bounds__(256) void attn_kernel(const ushort* __restrict__ qkv,
                                                   ushort* __restrict__ y) {
  constexpr int TQ = 64, TK = 64, DH = 64, C3 = 3 * C_;
  const int qt = blockIdx.x, h = blockIdx.y, b = blockIdx.z;
  const int tid = threadIdx.x;
  const int row = tid >> 2, sub = tid & 3;
  const int qg = qt * TQ + row;

  __shared__ ushort Klds[TK * DH];
  __shared__ ushort Vlds[TK * DH];
  __shared__ float Plds[TQ * (TK + 1)];  // stride 65: avoid 16-way bank conflict

  // Q row (pre-scaled by 1/sqrt(D)) in registers
  float q[DH];
  {
    const ushort* qrow = qkv + (size_t)(b * T_ + qg) * C3 + h * DH;
#pragma unroll
    for (int c = 0; c < 8; ++c) {
      u16x8 u = *(const u16x8*)(qrow + c * 8);
#pragma unroll
      for (int j = 0; j < 8; ++j) q[c * 8 + j] = bf2f(u[j]) * 0.125f;
    }
  }

  float yacc[16];
#pragma unroll
  for (int j = 0; j < 16; ++j) yacc[j] = 0.f;
  float mrun = -1e30f, lrun = 0.f;

  const int ntiles = qt + 1;
  for (int kt = 0; kt < ntiles; ++kt) {
    __syncthreads();  // protect LDS reads of previous iteration
    // stage K/V tile (64x64 bf16 each)
#pragma unroll
    for (int i = 0; i < 2; ++i) {
      int cch = tid * 2 + i;
      int kr = cch >> 3, cc = (cch & 7) * 8;
      const ushort* src = qkv + (size_t)(b * T_ + kt * TK + kr) * C3 + C_ + h * DH + cc;
      *(u16x8*)&Klds[kr * DH + cc] = *(const u16x8*)src;
      *(u16x8*)&Vlds[kr * DH + cc] = *(const u16x8*)(src + C_);
    }
    __syncthreads();

    const bool diag = (kt == qt);
    // phase 2: raw scores for this thread's 16 k's -> Plds, track tile max
    float tmax = -1e30f;
#pragma unroll 2
    for (int kk = 0; kk < 16; ++kk) {
      int k = sub * 16 + kk;
      float acc = 0.f;
      const ushort* krow = &Klds[k * DH];
#pragma unroll
      for (int c = 0; c < 8; ++c) {
        u16x8 u = *(const u16x8*)(krow + c * 8);
#pragma unroll
        for (int j = 0; j < 8; ++j) acc = fmaf(q[c * 8 + j], bf2f(u[j]), acc);
      }
      if (diag && k > row) acc = -1e30f;
      Plds[row * (TK + 1) + k] = acc;
      tmax = fmaxf(tmax, acc);
    }
    tmax = fmaxf(tmax, __shfl_xor(tmax, 1, 4));
    tmax = fmaxf(tmax, __shfl_xor(tmax, 2, 4));
    float newm = fmaxf(mrun, tmax);
    float corr = __expf(mrun - newm);
    mrun = newm;
    float lsum = 0.f;
#pragma unroll 4
    for (int kk = 0; kk < 16; ++kk) {
      int k = sub * 16 + kk;
      float p = __expf(Plds[row * (TK + 1) + k] - mrun);
      Plds[row * (TK + 1) + k] = p;
      lsum += p;
    }
    lsum += __shfl_xor(lsum, 1, 4);
    lsum += __shfl_xor(lsum, 2, 4);
    lrun = lrun * corr + lsum;
#pragma unroll
    for (int j = 0; j < 16; ++j) yacc[j] *= corr;
    __syncthreads();
    // phase 3: y += P * V  (this thread owns d in [sub*16, sub*16+16))
    const int kmax = diag ? (row + 1) : TK;
    for (int k = 0; k < kmax; ++k) {
      float p = Plds[row * (TK + 1) + k];
      const ushort* vr = &Vlds[k * DH + sub * 16];
      u16x8 u0 = *(const u16x8*)vr;
      u16x8 u1 = *(const u16x8*)(vr + 8);
#pragma unroll
      for (int j = 0; j < 8; ++j) {
        yacc[j] = fmaf(p, bf2f(u0[j]), yacc[j]);
        yacc[8 + j] = fmaf(p, bf2f(u1[j]), yacc[8 + j]);
      }
    }
  }

  const float inv = 1.f / lrun;
  u16x8 o0, o1;
#pragma unroll
  for (int j = 0; j < 8; ++j) {
    o0[j] = f2bf(yacc[j] * inv);
    o1[j] = f2bf(yacc[8 + j] * inv);
  }
  ushort* dst = y + (size_t)(b * T_ + qg) * C_ + h * DH + sub * 16;
  *(u16x8*)dst = o0;
  *(u16x8*)(dst + 8) = o1;
}

extern "C" void kernel_launch(void* const* d_in, const int* in_sizes, int n_in,
                              void* d_out, int out_size, void* d_ws, size_t ws_size,
                              hipStream_t stream) {
  const float* x = (const float*)d_in[0];
  const float* W_attn = (const float*)d_in[1];
  const float* b_attn = (const float*)d_in[2];
  const float* W_proj = (const float*)d_in[3];
  const float* b_proj = (const float*)d_in[4];
  float* out = (float*)d_out;

  char* ws = (char*)d_ws;
  // ws layout (bytes):
  ushort* xb   = (ushort*)(ws);                        // 8192*1024*2  = 16,777,216
  ushort* Wta  = (ushort*)(ws + (size_t)16777216);     // 3072*1024*2  =  6,291,456
  ushort* Wtp  = (ushort*)(ws + (size_t)23068672);     // 1024*1024*2  =  2,097,152
  ushort* qkvb = (ushort*)(ws + (size_t)25165824);     // 8192*3072*2  = 50,331,648
  ushort* yb   = (ushort*)(ws + (size_t)75497472);     // 8192*1024*2  = 16,777,216
                                                       // total 92,274,688 B

  cast_f32_bf16<<<2048, 256, 0, stream>>>(x, xb, (B_ * T_ * C_) / 4);
  transpose_cast<<<dim3(48, 16), 256, 0, stream>>>(W_attn, Wta, C_, 3 * C_);
  transpose_cast<<<dim3(16, 16), 256, 0, stream>>>(W_proj, Wtp, C_, C_);
  gemm_bt<1><<<dim3(24, 64), 256, 0, stream>>>(xb, Wta, b_attn, (void*)qkvb,
                                               B_ * T_, 3 * C_, C_);
  attn_kernel<<<dim3(T_ / 64, H_, B_), 256, 0, stream>>>(qkvb, yb);
  gemm_bt<0><<<dim3(8, 64), 256, 0, stream>>>(yb, Wtp, b_proj, (void*)out,
                                              B_ * T_, C_, C_);
}

// Round 2
// 398.181 us; speedup vs baseline: 4.4442x; 4.4442x over previous
//
#include <hip/hip_runtime.h>
#include <hip/hip_bf16.h>

#define B_ 4
#define T_ 2048
#define C_ 1024
#define H_ 16
#define D_ 64

using u16x4 = __attribute__((ext_vector_type(4))) unsigned short;
using u16x8 = __attribute__((ext_vector_type(8))) unsigned short;
using s16x8 = __attribute__((ext_vector_type(8))) short;
using f32x4v = __attribute__((ext_vector_type(4))) float;

__device__ inline float bf2f(unsigned short u) {
  return __uint_as_float(((unsigned int)u) << 16);
}
__device__ inline unsigned short f2bf(float f) {
  unsigned int x = __float_as_uint(f);
  unsigned int r = (x + 0x7fffu + ((x >> 16) & 1u)) >> 16;
  return (unsigned short)r;
}

// ---------------- elementwise f32 -> bf16 cast ----------------
__global__ __launch_bounds__(256) void cast_f32_bf16(const float* __restrict__ in,
                                                     ushort* __restrict__ out, int n4) {
  const int stride = gridDim.x * blockDim.x;
  for (int i = blockIdx.x * blockDim.x + threadIdx.x; i < n4; i += stride) {
    float4 v = ((const float4*)in)[i];
    u16x4 o = {f2bf(v.x), f2bf(v.y), f2bf(v.z), f2bf(v.w)};
    ((u16x4*)out)[i] = o;
  }
}

// ---------------- transpose + cast: W[K][N] f32 -> Wt[N][K] bf16 ----------------
__global__ __launch_bounds__(256) void transpose_cast(const float* __restrict__ W,
                                                      ushort* __restrict__ Wt, int K, int N) {
  __shared__ float tile[64][65];
  const int n0 = blockIdx.x * 64, k0 = blockIdx.y * 64;
  const int tid = threadIdx.x;
  const int tr = tid >> 4, tc4 = (tid & 15) * 4;
#pragma unroll
  for (int i = 0; i < 4; ++i) {
    int r = tr + i * 16;
    float4 v = *(const float4*)&W[(size_t)(k0 + r) * N + n0 + tc4];
    tile[r][tc4 + 0] = v.x; tile[r][tc4 + 1] = v.y;
    tile[r][tc4 + 2] = v.z; tile[r][tc4 + 3] = v.w;
  }
  __syncthreads();
#pragma unroll
  for (int i = 0; i < 4; ++i) {
    int n = tr + i * 16;
    u16x4 o;
#pragma unroll
    for (int j = 0; j < 4; ++j) o[j] = f2bf(tile[tc4 + j][n]);
    *(u16x4*)&Wt[(size_t)(n0 + n) * K + k0 + tc4] = o;
  }
}

// ---------------- GEMM: C[M][N] = A[M][K] * Bt[N][K]^T + bias ----------------
template <int BF16OUT>
__global__ __launch_bounds__(256) void gemm_bt(const ushort* __restrict__ A,
                                               const ushort* __restrict__ Bt,
                                               const float* __restrict__ bias,
                                               void* __restrict__ Cout,
                                               int M, int N, int K) {
  constexpr int BM = 128, BN = 128, BK = 64;
  __shared__ ushort Alds[BM * BK];
  __shared__ ushort Blds[BN * BK];
  const int tid = threadIdx.x;
  const int lane = tid & 63;
  const int w = tid >> 6;
  const int wr = w >> 1, wc = w & 1;
  const int m0 = blockIdx.y * BM, n0 = blockIdx.x * BN;

  f32x4v acc[4][4] = {};

  const int ra = w * 32 + (lane >> 3);
  const int ca = (lane & 7) * 8;

  for (int k0 = 0; k0 < K; k0 += BK) {
#pragma unroll
    for (int i = 0; i < 4; ++i) {
      const ushort* ga = A + (size_t)(m0 + ra + i * 8) * K + k0 + ca;
      __builtin_amdgcn_global_load_lds(
          (const __attribute__((address_space(1))) void*)ga,
          (__attribute__((address_space(3))) void*)&Alds[w * 2048 + i * 512], 16, 0, 0);
      const ushort* gb = Bt + (size_t)(n0 + ra + i * 8) * K + k0 + ca;
      __builtin_amdgcn_global_load_lds(
          (const __attribute__((address_space(1))) void*)gb,
          (__attribute__((address_space(3))) void*)&Blds[w * 2048 + i * 512], 16, 0, 0);
    }
    __syncthreads();
#pragma unroll
    for (int ks = 0; ks < 2; ++ks) {
      s16x8 af[4], bfr[4];
#pragma unroll
      for (int m = 0; m < 4; ++m)
        af[m] = *(const s16x8*)&Alds[(wr * 64 + m * 16 + (lane & 15)) * BK + ks * 32 + ((lane >> 4) * 8)];
#pragma unroll
      for (int n = 0; n < 4; ++n)
        bfr[n] = *(const s16x8*)&Blds[(wc * 64 + n * 16 + (lane & 15)) * BK + ks * 32 + ((lane >> 4) * 8)];
#pragma unroll
      for (int m = 0; m < 4; ++m)
#pragma unroll
        for (int n = 0; n < 4; ++n)
          acc[m][n] = __builtin_amdgcn_mfma_f32_16x16x32_bf16(af[m], bfr[n], acc[m][n], 0, 0, 0);
    }
    __syncthreads();
  }

#pragma unroll
  for (int m = 0; m < 4; ++m) {
    const int rg = m0 + wr * 64 + m * 16 + ((lane >> 4) * 4);
#pragma unroll
    for (int n = 0; n < 4; ++n) {
      const int cg = n0 + wc * 64 + n * 16 + (lane & 15);
      const float bv = bias[cg];
#pragma unroll
      for (int r2 = 0; r2 < 4; ++r2) {
        float v = acc[m][n][r2] + bv;
        if constexpr (BF16OUT)
          ((ushort*)Cout)[(size_t)(rg + r2) * N + cg] = f2bf(v);
        else
          ((float*)Cout)[(size_t)(rg + r2) * N + cg] = v;
      }
    }
  }
}

// ---------------- MFMA causal flash attention ----------------
// qkv: [B*T][3C] bf16 (q|k|v). y: [B*T][C] bf16.
// Block: (qt, h, b). 4 waves; wave w owns q-rows [qt*64+w*16, +16).
// LDS: Klds [k][d] (read-swizzled via pre-swizzled gload src),
//      Vt [d][kv] (reg-staged transpose, swizzled), Qp: Q staging then P.
__global__ __launch_bounds__(256) void attn_kernel(const ushort* __restrict__ qkv,
                                                   ushort* __restrict__ y) {
  constexpr int C3 = 3 * C_;
  const int qt = blockIdx.x, h = blockIdx.y, b = blockIdx.z;
  const int tid = threadIdx.x;
  const int lane = tid & 63;
  const int w = tid >> 6;
  const int ko8 = (lane >> 4) * 8;   // k-elem offset within a 32-chunk for A/B frags
  const int l15 = lane & 15;

  __shared__ __align__(16) ushort Klds[64 * 64];
  __shared__ __align__(16) ushort Vt[64 * 64];
  __shared__ __align__(16) ushort Qp[64 * 64];   // Q staging, then P (per-wave 1024 elems)

  // ---- stage Q (swizzled source -> linear LDS; reads below use XOR swizzle) ----
#pragma unroll
  for (int i = 0; i < 2; ++i) {
    int s = (w * 2 + i) * 1024 + lane * 16;          // byte slot in 8KB buffer
    int row = s >> 7;                                // block-local q row
    int cb = (s & 127) ^ ((row & 7) << 4);           // swizzled byte col
    const ushort* src = qkv + (size_t)(b * T_ + qt * 64 + row) * C3 + h * D_ + (cb >> 1);
    __builtin_amdgcn_global_load_lds(
        (const __attribute__((address_space(1))) void*)src,
        (__attribute__((address_space(3))) void*)&Qp[(w * 2 + i) * 512], 16, 0, 0);
  }
  __syncthreads();

  s16x8 qf0, qf1;
  {
    int qrow = w * 16 + l15;
    int swz = (qrow & 7) << 3;
    qf0 = *(const s16x8*)&Qp[qrow * 64 + ((0  + ko8) ^ swz)];
    qf1 = *(const s16x8*)&Qp[qrow * 64 + ((32 + ko8) ^ swz)];
  }

  f32x4v yacc[4] = {};
  float mrun[4], lrun[4];
#pragma unroll
  for (int r = 0; r < 4; ++r) { mrun[r] = -1e30f; lrun[r] = 0.f; }

  const int kv = lane;        // V staging: this lane's kv row
  const int d0 = w * 16;      // V staging: this wave's d block

  for (int kt = 0; kt <= qt; ++kt) {
    // V tile -> regs (issue early)
    const ushort* vsrc = qkv + (size_t)(b * T_ + kt * 64 + kv) * C3 + 2 * C_ + h * D_ + d0;
    u16x8 vv0 = *(const u16x8*)vsrc;
    u16x8 vv1 = *(const u16x8*)(vsrc + 8);

    __syncthreads();   // previous iteration's LDS reads (and Q-frag reads) done

    // K tile -> LDS via global_load_lds, pre-swizzled source
#pragma unroll
    for (int i = 0; i < 2; ++i) {
      int s = (w * 2 + i) * 1024 + lane * 16;
      int row = s >> 7;
      int cb = (s & 127) ^ ((row & 7) << 4);
      const ushort* src = qkv + (size_t)(b * T_ + kt * 64 + row) * C3 + C_ + h * D_ + (cb >> 1);
      __builtin_amdgcn_global_load_lds(
          (const __attribute__((address_space(1))) void*)src,
          (__attribute__((address_space(3))) void*)&Klds[(w * 2 + i) * 512], 16, 0, 0);
    }
    // V transpose -> LDS (swizzled scalar writes, conflict-free pattern)
#pragma unroll
    for (int j = 0; j < 8; ++j) {
      int d = d0 + j;
      Vt[d * 64 + (kv ^ ((d & 7) << 3))] = vv0[j];
      int d2 = d0 + 8 + j;
      Vt[d2 * 64 + (kv ^ ((d2 & 7) << 3))] = vv1[j];
    }
    __syncthreads();   // staging visible (vmcnt(0)+lgkmcnt(0) drain at barrier)

    const bool diag = (kt == qt);
    const int NT = diag ? (w + 1) : 4;            // k sub-tiles to compute
    const int CM = diag ? ((w >= 2) ? 2 : 1) : 2; // 32-wide kv chunks for PV

    // ---- QK^T ----
    f32x4v accv[4];
#pragma unroll
    for (int n = 0; n < 4; ++n) {
      if (n >= NT) continue;
      int kr = n * 16 + l15;
      int swz = (kr & 7) << 3;
      s16x8 kf0 = *(const s16x8*)&Klds[kr * 64 + ((0  + ko8) ^ swz)];
      s16x8 kf1 = *(const s16x8*)&Klds[kr * 64 + ((32 + ko8) ^ swz)];
      f32x4v a = {0.f, 0.f, 0.f, 0.f};
      a = __builtin_amdgcn_mfma_f32_16x16x32_bf16(qf0, kf0, a, 0, 0, 0);
      a = __builtin_amdgcn_mfma_f32_16x16x32_bf16(qf1, kf1, a, 0, 0, 0);
      if (diag && n == NT - 1) {
#pragma unroll
        for (int r = 0; r < 4; ++r)
          if (n * 16 + l15 > w * 16 + (lane >> 4) * 4 + r) a[r] = -1e30f;
      }
      accv[n] = a;
    }

    // ---- online softmax (scale 1/8 folded in) ----
    float corr_[4];
#pragma unroll
    for (int r = 0; r < 4; ++r) {
      float mx = -3e38f;
#pragma unroll
      for (int n = 0; n < 4; ++n)
        if (n < NT) mx = fmaxf(mx, accv[n][r]);
      mx = fmaxf(mx, __shfl_xor(mx, 1));
      mx = fmaxf(mx, __shfl_xor(mx, 2));
      mx = fmaxf(mx, __shfl_xor(mx, 4));
      mx = fmaxf(mx, __shfl_xor(mx, 8));
      float nm = fmaxf(mrun[r], mx * 0.125f);
      corr_[r] = __expf(mrun[r] - nm);
      mrun[r] = nm;
    }
#pragma unroll
    for (int r = 0; r < 4; ++r) {
      float ls = 0.f;
#pragma unroll
      for (int n = 0; n < 4; ++n) {
        if (n < NT) {
          float p = __expf(fmaf(accv[n][r], 0.125f, -mrun[r]));
          accv[n][r] = p;
          ls += p;
        }
      }
      ls += __shfl_xor(ls, 1);
      ls += __shfl_xor(ls, 2);
      ls += __shfl_xor(ls, 4);
      ls += __shfl_xor(ls, 8);
      lrun[r] = fmaf(lrun[r], corr_[r], ls);
#pragma unroll
      for (int nd = 0; nd < 4; ++nd) yacc[nd][r] *= corr_[r];
    }

    // ---- P -> LDS (bf16, A-frag layout, swizzled; per-wave region) ----
    ushort* Pw = &Qp[w * 1024];
#pragma unroll
    for (int n = 0; n < 4; ++n) {
      bool valid = (n < NT);
      bool zero = (n >= NT) && (n < 2 * CM);
      if (!valid && !zero) continue;
#pragma unroll
      for (int r = 0; r < 4; ++r) {
        int qp = (lane >> 4) * 4 + r;
        int k = n * 16 + l15;
        Pw[qp * 64 + (k ^ ((qp & 7) << 3))] = valid ? f2bf(accv[n][r]) : (ushort)0;
      }
    }

    // ---- PV ----
    s16x8 pf0, pf1 = {};
    {
      int swz = (l15 & 7) << 3;
      pf0 = *(const s16x8*)&Pw[l15 * 64 + ((0 + ko8) ^ swz)];
      if (CM > 1) pf1 = *(const s16x8*)&Pw[l15 * 64 + ((32 + ko8) ^ swz)];
    }
#pragma unroll
    for (int nd = 0; nd < 4; ++nd) {
      int d = nd * 16 + l15;
      int swz = (d & 7) << 3;
      s16x8 vf0 = *(const s16x8*)&Vt[d * 64 + ((0 + ko8) ^ swz)];
      yacc[nd] = __builtin_amdgcn_mfma_f32_16x16x32_bf16(pf0, vf0, yacc[nd], 0, 0, 0);
      if (CM > 1) {
        s16x8 vf1 = *(const s16x8*)&Vt[d * 64 + ((32 + ko8) ^ swz)];
        yacc[nd] = __builtin_amdgcn_mfma_f32_16x16x32_bf16(pf1, vf1, yacc[nd], 0, 0, 0);
      }
    }
  }

  // ---- epilogue ----
#pragma unroll
  for (int r = 0; r < 4; ++r) {
    float inv = 1.f / lrun[r];
    int qg = qt * 64 + w * 16 + (lane >> 4) * 4 + r;
    ushort* dst = y + (size_t)(b * T_ + qg) * C_ + h * D_ + l15;
#pragma unroll
    for (int nd = 0; nd < 4; ++nd) dst[nd * 16] = f2bf(yacc[nd][r] * inv);
  }
}

extern "C" void kernel_launch(void* const* d_in, const int* in_sizes, int n_in,
                              void* d_out, int out_size, void* d_ws, size_t ws_size,
                              hipStream_t stream) {
  const float* x = (const float*)d_in[0];
  const float* W_attn = (const float*)d_in[1];
  const float* b_attn = (const float*)d_in[2];
  const float* W_proj = (const float*)d_in[3];
  const float* b_proj = (const float*)d_in[4];
  float* out = (float*)d_out;

  char* ws = (char*)d_ws;
  ushort* xb   = (ushort*)(ws);                        // 16,777,216 B
  ushort* Wta  = (ushort*)(ws + (size_t)16777216);     //  6,291,456 B
  ushort* Wtp  = (ushort*)(ws + (size_t)23068672);     //  2,097,152 B
  ushort* qkvb = (ushort*)(ws + (size_t)25165824);     // 50,331,648 B
  ushort* yb   = (ushort*)(ws + (size_t)75497472);     // 16,777,216 B

  cast_f32_bf16<<<2048, 256, 0, stream>>>(x, xb, (B_ * T_ * C_) / 4);
  transpose_cast<<<dim3(48, 16), 256, 0, stream>>>(W_attn, Wta, C_, 3 * C_);
  transpose_cast<<<dim3(16, 16), 256, 0, stream>>>(W_proj, Wtp, C_, C_);
  gemm_bt<1><<<dim3(24, 64), 256, 0, stream>>>(xb, Wta, b_attn, (void*)qkvb,
                                               B_ * T_, 3 * C_, C_);
  attn_kernel<<<dim3(T_ / 64, H_, B_), 256, 0, stream>>>(qkvb, yb);
  gemm_bt<0><<<dim3(8, 64), 256, 0, stream>>>(yb, Wtp, b_proj, (void*)out,
                                              B_ * T_, C_, C_);
}

// Round 3
// 334.149 us; speedup vs baseline: 5.2958x; 1.1916x over previous
//
#include <hip/hip_runtime.h>
#include <hip/hip_bf16.h>

#define B_ 4
#define T_ 2048
#define C_ 1024
#define H_ 16
#define D_ 64

using u16x4 = __attribute__((ext_vector_type(4))) unsigned short;
using u16x8 = __attribute__((ext_vector_type(8))) unsigned short;
using s16x8 = __attribute__((ext_vector_type(8))) short;
using f32x4v = __attribute__((ext_vector_type(4))) float;

__device__ inline float bf2f(unsigned short u) {
  return __uint_as_float(((unsigned int)u) << 16);
}
__device__ inline unsigned short f2bf(float f) {
  unsigned int x = __float_as_uint(f);
  unsigned int r = (x + 0x7fffu + ((x >> 16) & 1u)) >> 16;
  return (unsigned short)r;
}

// ---------------- elementwise f32 -> bf16 cast ----------------
__global__ __launch_bounds__(256) void cast_f32_bf16(const float* __restrict__ in,
                                                     ushort* __restrict__ out, int n4) {
  const int stride = gridDim.x * blockDim.x;
  for (int i = blockIdx.x * blockDim.x + threadIdx.x; i < n4; i += stride) {
    float4 v = ((const float4*)in)[i];
    u16x4 o = {f2bf(v.x), f2bf(v.y), f2bf(v.z), f2bf(v.w)};
    ((u16x4*)out)[i] = o;
  }
}

// ---------------- transpose + cast: W[K][N] f32 -> Wt[N][K] bf16 ----------------
__global__ __launch_bounds__(256) void transpose_cast(const float* __restrict__ W,
                                                      ushort* __restrict__ Wt, int K, int N) {
  __shared__ float tile[64][65];
  const int n0 = blockIdx.x * 64, k0 = blockIdx.y * 64;
  const int tid = threadIdx.x;
  const int tr = tid >> 4, tc4 = (tid & 15) * 4;
#pragma unroll
  for (int i = 0; i < 4; ++i) {
    int r = tr + i * 16;
    float4 v = *(const float4*)&W[(size_t)(k0 + r) * N + n0 + tc4];
    tile[r][tc4 + 0] = v.x; tile[r][tc4 + 1] = v.y;
    tile[r][tc4 + 2] = v.z; tile[r][tc4 + 3] = v.w;
  }
  __syncthreads();
#pragma unroll
  for (int i = 0; i < 4; ++i) {
    int n = tr + i * 16;
    u16x4 o;
#pragma unroll
    for (int j = 0; j < 4; ++j) o[j] = f2bf(tile[tc4 + j][n]);
    *(u16x4*)&Wt[(size_t)(n0 + n) * K + k0 + tc4] = o;
  }
}

// ---------------- GEMM: C[M][N] = A[M][K] * Bt[N][K]^T + bias ----------------
template <int BF16OUT>
__global__ __launch_bounds__(256) void gemm_bt(const ushort* __restrict__ A,
                                               const ushort* __restrict__ Bt,
                                               const float* __restrict__ bias,
                                               void* __restrict__ Cout,
                                               int M, int N, int K) {
  constexpr int BM = 128, BN = 128, BK = 64;
  __shared__ ushort Alds[BM * BK];
  __shared__ ushort Blds[BN * BK];
  const int tid = threadIdx.x;
  const int lane = tid & 63;
  const int w = tid >> 6;
  const int wr = w >> 1, wc = w & 1;
  const int m0 = blockIdx.y * BM, n0 = blockIdx.x * BN;

  f32x4v acc[4][4] = {};

  const int ra = w * 32 + (lane >> 3);
  const int ca = (lane & 7) * 8;

  for (int k0 = 0; k0 < K; k0 += BK) {
#pragma unroll
    for (int i = 0; i < 4; ++i) {
      const ushort* ga = A + (size_t)(m0 + ra + i * 8) * K + k0 + ca;
      __builtin_amdgcn_global_load_lds(
          (const __attribute__((address_space(1))) void*)ga,
          (__attribute__((address_space(3))) void*)&Alds[w * 2048 + i * 512], 16, 0, 0);
      const ushort* gb = Bt + (size_t)(n0 + ra + i * 8) * K + k0 + ca;
      __builtin_amdgcn_global_load_lds(
          (const __attribute__((address_space(1))) void*)gb,
          (__attribute__((address_space(3))) void*)&Blds[w * 2048 + i * 512], 16, 0, 0);
    }
    __syncthreads();
#pragma unroll
    for (int ks = 0; ks < 2; ++ks) {
      s16x8 af[4], bfr[4];
#pragma unroll
      for (int m = 0; m < 4; ++m)
        af[m] = *(const s16x8*)&Alds[(wr * 64 + m * 16 + (lane & 15)) * BK + ks * 32 + ((lane >> 4) * 8)];
#pragma unroll
      for (int n = 0; n < 4; ++n)
        bfr[n] = *(const s16x8*)&Blds[(wc * 64 + n * 16 + (lane & 15)) * BK + ks * 32 + ((lane >> 4) * 8)];
#pragma unroll
      for (int m = 0; m < 4; ++m)
#pragma unroll
        for (int n = 0; n < 4; ++n)
          acc[m][n] = __builtin_amdgcn_mfma_f32_16x16x32_bf16(af[m], bfr[n], acc[m][n], 0, 0, 0);
    }
    __syncthreads();
  }

#pragma unroll
  for (int m = 0; m < 4; ++m) {
    const int rg = m0 + wr * 64 + m * 16 + ((lane >> 4) * 4);
#pragma unroll
    for (int n = 0; n < 4; ++n) {
      const int cg = n0 + wc * 64 + n * 16 + (lane & 15);
      const float bv = bias[cg];
#pragma unroll
      for (int r2 = 0; r2 < 4; ++r2) {
        float v = acc[m][n][r2] + bv;
        if constexpr (BF16OUT)
          ((ushort*)Cout)[(size_t)(rg + r2) * N + cg] = f2bf(v);
        else
          ((float*)Cout)[(size_t)(rg + r2) * N + cg] = v;
      }
    }
  }
}

// ---------------- MFMA causal flash attention, 2-phase pipelined ----------------
// qkv: [B*T][3C] bf16 (q|k|v). y: [B*T][C] bf16.
// Block: (qt,h,b), 4 waves, 64 q-rows. K/Vt double-buffered; 1 barrier/iter.
__global__ __launch_bounds__(256, 4) void attn_kernel(const ushort* __restrict__ qkv,
                                                      ushort* __restrict__ y) {
  constexpr int C3 = 3 * C_;
  const int qt = (int)gridDim.x - 1 - (int)blockIdx.x;  // longest blocks first
  const int h = blockIdx.y, b = blockIdx.z;
  const int tid = threadIdx.x;
  const int lane = tid & 63;
  const int w = tid >> 6;
  const int ko8 = (lane >> 4) * 8;
  const int l15 = lane & 15;

  __shared__ __align__(16) ushort Klds[2][64 * 64];
  __shared__ __align__(16) ushort Vt[2][64 * 64];
  __shared__ __align__(16) ushort Qp[64 * 64];  // Q staging, then per-wave P

  // swizzled staging source offsets (row-major 64x64 bf16, 16B granules)
  const int s_slot = lane * 16;
  const int s_row0 = (w * 2 + 0) * 8 + (s_slot >> 7);
  const int s_row1 = (w * 2 + 1) * 8 + (s_slot >> 7);
  const int s_cb0 = ((s_slot & 127) ^ ((s_row0 & 7) << 4)) >> 1;  // elem offset
  const int s_cb1 = ((s_slot & 127) ^ ((s_row1 & 7) << 4)) >> 1;

  // ---- prologue: stage Q, K0; load V0 regs ----
  {
    const ushort* q0 = qkv + (size_t)(b * T_ + qt * 64 + s_row0) * C3 + h * D_ + s_cb0;
    const ushort* q1 = qkv + (size_t)(b * T_ + qt * 64 + s_row1) * C3 + h * D_ + s_cb1;
    __builtin_amdgcn_global_load_lds((const __attribute__((address_space(1))) void*)q0,
        (__attribute__((address_space(3))) void*)&Qp[(w * 2 + 0) * 512], 16, 0, 0);
    __builtin_amdgcn_global_load_lds((const __attribute__((address_space(1))) void*)q1,
        (__attribute__((address_space(3))) void*)&Qp[(w * 2 + 1) * 512], 16, 0, 0);
    const ushort* k0p = qkv + (size_t)(b * T_ + s_row0) * C3 + C_ + h * D_ + s_cb0;
    const ushort* k1p = qkv + (size_t)(b * T_ + s_row1) * C3 + C_ + h * D_ + s_cb1;
    __builtin_amdgcn_global_load_lds((const __attribute__((address_space(1))) void*)k0p,
        (__attribute__((address_space(3))) void*)&Klds[0][(w * 2 + 0) * 512], 16, 0, 0);
    __builtin_amdgcn_global_load_lds((const __attribute__((address_space(1))) void*)k1p,
        (__attribute__((address_space(3))) void*)&Klds[0][(w * 2 + 1) * 512], 16, 0, 0);
  }
  const int kvr = lane;       // V staging row
  const int d0 = w * 16;      // V staging d-block
  u16x8 vn0, vn1;
  {
    const ushort* vsrc = qkv + (size_t)(b * T_ + kvr) * C3 + 2 * C_ + h * D_ + d0;
    vn0 = *(const u16x8*)vsrc;
    vn1 = *(const u16x8*)(vsrc + 8);
  }
  __syncthreads();

  // ---- Q fragments (pre-scaled by 1/sqrt(D)=0.125, exact) ----
  s16x8 qf0, qf1;
  {
    int qrow = w * 16 + l15;
    int swz = (qrow & 7) << 3;
    qf0 = *(const s16x8*)&Qp[qrow * 64 + ((0 + ko8) ^ swz)];
    qf1 = *(const s16x8*)&Qp[qrow * 64 + ((32 + ko8) ^ swz)];
#pragma unroll
    for (int j = 0; j < 8; ++j) {
      qf0[j] = (short)f2bf(bf2f((unsigned short)qf0[j]) * 0.125f);
      qf1[j] = (short)f2bf(bf2f((unsigned short)qf1[j]) * 0.125f);
    }
  }
  // ---- Vt[0] write ----
#pragma unroll
  for (int j = 0; j < 8; ++j) {
    int d = d0 + j, d2 = d0 + 8 + j;
    Vt[0][d * 64 + (kvr ^ ((d & 7) << 3))] = vn0[j];
    Vt[0][d2 * 64 + (kvr ^ ((d2 & 7) << 3))] = vn1[j];
  }
  __syncthreads();

  f32x4v yacc[4] = {};
  float mrun[4], lrun[4];
#pragma unroll
  for (int r = 0; r < 4; ++r) { mrun[r] = -1e30f; lrun[r] = 0.f; }

  const int nt = qt + 1;
  for (int t = 0; t < nt; ++t) {
    const int cur = t & 1;
    // ---- issue next tile's staging (V regs first, then K gload) ----
    if (t + 1 < nt) {
      const ushort* vsrc = qkv + (size_t)(b * T_ + (t + 1) * 64 + kvr) * C3 + 2 * C_ + h * D_ + d0;
      vn0 = *(const u16x8*)vsrc;
      vn1 = *(const u16x8*)(vsrc + 8);
      const ushort* k0p = qkv + (size_t)(b * T_ + (t + 1) * 64 + s_row0) * C3 + C_ + h * D_ + s_cb0;
      const ushort* k1p = qkv + (size_t)(b * T_ + (t + 1) * 64 + s_row1) * C3 + C_ + h * D_ + s_cb1;
      __builtin_amdgcn_global_load_lds((const __attribute__((address_space(1))) void*)k0p,
          (__attribute__((address_space(3))) void*)&Klds[cur ^ 1][(w * 2 + 0) * 512], 16, 0, 0);
      __builtin_amdgcn_global_load_lds((const __attribute__((address_space(1))) void*)k1p,
          (__attribute__((address_space(3))) void*)&Klds[cur ^ 1][(w * 2 + 1) * 512], 16, 0, 0);
    }

    const bool diag = (t == qt);
    const int NT = diag ? (w + 1) : 4;
    const int CM = diag ? ((w >= 2) ? 2 : 1) : 2;

    // ---- QK^T ----
    f32x4v accv[4];
    __builtin_amdgcn_s_setprio(1);
#pragma unroll
    for (int n = 0; n < 4; ++n) {
      if (n >= NT) continue;
      int kr = n * 16 + l15;
      int swz = (kr & 7) << 3;
      s16x8 kf0 = *(const s16x8*)&Klds[cur][kr * 64 + ((0 + ko8) ^ swz)];
      s16x8 kf1 = *(const s16x8*)&Klds[cur][kr * 64 + ((32 + ko8) ^ swz)];
      f32x4v a = {0.f, 0.f, 0.f, 0.f};
      a = __builtin_amdgcn_mfma_f32_16x16x32_bf16(qf0, kf0, a, 0, 0, 0);
      a = __builtin_amdgcn_mfma_f32_16x16x32_bf16(qf1, kf1, a, 0, 0, 0);
      if (diag && n == NT - 1) {
#pragma unroll
        for (int r = 0; r < 4; ++r)
          if (n * 16 + l15 > w * 16 + (lane >> 4) * 4 + r) a[r] = -1e30f;
      }
      accv[n] = a;
    }
    __builtin_amdgcn_s_setprio(0);

    // ---- online softmax (Q pre-scaled; exact defer of no-op rescale) ----
    float nm[4];
#pragma unroll
    for (int r = 0; r < 4; ++r) {
      float mx = -3e38f;
#pragma unroll
      for (int n = 0; n < 4; ++n)
        if (n < NT) mx = fmaxf(mx, accv[n][r]);
      mx = fmaxf(mx, __shfl_xor(mx, 1));
      mx = fmaxf(mx, __shfl_xor(mx, 2));
      mx = fmaxf(mx, __shfl_xor(mx, 4));
      mx = fmaxf(mx, __shfl_xor(mx, 8));
      nm[r] = fmaxf(mrun[r], mx);
    }
    bool up = (nm[0] > mrun[0]) | (nm[1] > mrun[1]) | (nm[2] > mrun[2]) | (nm[3] > mrun[3]);
    if (__ballot(up) != 0ull) {
#pragma unroll
      for (int r = 0; r < 4; ++r) {
        float corr = __expf(mrun[r] - nm[r]);
        mrun[r] = nm[r];
        lrun[r] *= corr;
#pragma unroll
        for (int nd = 0; nd < 4; ++nd) yacc[nd][r] *= corr;
      }
    }
#pragma unroll
    for (int r = 0; r < 4; ++r) {
      float ls = 0.f;
#pragma unroll
      for (int n = 0; n < 4; ++n) {
        if (n < NT) {
          float p = __expf(accv[n][r] - mrun[r]);
          accv[n][r] = p;
          ls += p;
        }
      }
      ls += __shfl_xor(ls, 1);
      ls += __shfl_xor(ls, 2);
      ls += __shfl_xor(ls, 4);
      ls += __shfl_xor(ls, 8);
      lrun[r] += ls;
    }

    // ---- P -> LDS (bf16, A-frag layout, swizzled; per-wave region) ----
    ushort* Pw = &Qp[w * 1024];
#pragma unroll
    for (int n = 0; n < 4; ++n) {
      bool valid = (n < NT);
      bool zero = (n >= NT) && (n < 2 * CM);
      if (!valid && !zero) continue;
#pragma unroll
      for (int r = 0; r < 4; ++r) {
        int qp = (lane >> 4) * 4 + r;
        int k = n * 16 + l15;
        Pw[qp * 64 + (k ^ ((qp & 7) << 3))] = valid ? f2bf(accv[n][r]) : (ushort)0;
      }
    }

    // ---- PV ----
    s16x8 pf0, pf1 = {};
    {
      int swz = (l15 & 7) << 3;
      pf0 = *(const s16x8*)&Pw[l15 * 64 + ((0 + ko8) ^ swz)];
      if (CM > 1) pf1 = *(const s16x8*)&Pw[l15 * 64 + ((32 + ko8) ^ swz)];
    }
    __builtin_amdgcn_s_setprio(1);
#pragma unroll
    for (int nd = 0; nd < 4; ++nd) {
      int d = nd * 16 + l15;
      int swz = (d & 7) << 3;
      s16x8 vf0 = *(const s16x8*)&Vt[cur][d * 64 + ((0 + ko8) ^ swz)];
      yacc[nd] = __builtin_amdgcn_mfma_f32_16x16x32_bf16(pf0, vf0, yacc[nd], 0, 0, 0);
      if (CM > 1) {
        s16x8 vf1 = *(const s16x8*)&Vt[cur][d * 64 + ((32 + ko8) ^ swz)];
        yacc[nd] = __builtin_amdgcn_mfma_f32_16x16x32_bf16(pf1, vf1, yacc[nd], 0, 0, 0);
      }
    }
    __builtin_amdgcn_s_setprio(0);

    // ---- write next V tile into other buffer ----
    if (t + 1 < nt) {
#pragma unroll
      for (int j = 0; j < 8; ++j) {
        int d = d0 + j, d2 = d0 + 8 + j;
        Vt[cur ^ 1][d * 64 + (kvr ^ ((d & 7) << 3))] = vn0[j];
        Vt[cur ^ 1][d2 * 64 + (kvr ^ ((d2 & 7) << 3))] = vn1[j];
      }
    }
    __syncthreads();
  }

  // ---- epilogue ----
#pragma unroll
  for (int r = 0; r < 4; ++r) {
    float inv = 1.f / lrun[r];
    int qg = qt * 64 + w * 16 + (lane >> 4) * 4 + r;
    ushort* dst = y + (size_t)(b * T_ + qg) * C_ + h * D_ + l15;
#pragma unroll
    for (int nd = 0; nd < 4; ++nd) dst[nd * 16] = f2bf(yacc[nd][r] * inv);
  }
}

extern "C" void kernel_launch(void* const* d_in, const int* in_sizes, int n_in,
                              void* d_out, int out_size, void* d_ws, size_t ws_size,
                              hipStream_t stream) {
  const float* x = (const float*)d_in[0];
  const float* W_attn = (const float*)d_in[1];
  const float* b_attn = (const float*)d_in[2];
  const float* W_proj = (const float*)d_in[3];
  const float* b_proj = (const float*)d_in[4];
  float* out = (float*)d_out;

  char* ws = (char*)d_ws;
  ushort* xb   = (ushort*)(ws);                        // 16,777,216 B
  ushort* Wta  = (ushort*)(ws + (size_t)16777216);     //  6,291,456 B
  ushort* Wtp  = (ushort*)(ws + (size_t)23068672);     //  2,097,152 B
  ushort* qkvb = (ushort*)(ws + (size_t)25165824);     // 50,331,648 B
  ushort* yb   = (ushort*)(ws + (size_t)75497472);     // 16,777,216 B

  cast_f32_bf16<<<2048, 256, 0, stream>>>(x, xb, (B_ * T_ * C_) / 4);
  transpose_cast<<<dim3(48, 16), 256, 0, stream>>>(W_attn, Wta, C_, 3 * C_);
  transpose_cast<<<dim3(16, 16), 256, 0, stream>>>(W_proj, Wtp, C_, C_);
  gemm_bt<1><<<dim3(24, 64), 256, 0, stream>>>(xb, Wta, b_attn, (void*)qkvb,
                                               B_ * T_, 3 * C_, C_);
  attn_kernel<<<dim3(T_ / 64, H_, B_), 256, 0, stream>>>(qkvb, yb);
  gemm_bt<0><<<dim3(8, 64), 256, 0, stream>>>(yb, Wtp, b_proj, (void*)out,
                                              B_ * T_, C_, C_);
}